// Round 1
// baseline (654.237 us; speedup 1.0000x reference)
//
#include <hip/hip_runtime.h>
#include <hip/hip_bf16.h>

typedef unsigned short ushort_t;
typedef short short8 __attribute__((ext_vector_type(8)));
typedef float f32x4 __attribute__((ext_vector_type(4)));

#define J_TOT 43
#define J6 13
#define D_DIM 512
#define BT 3136
#define OUTW 168

__device__ __forceinline__ unsigned short bf16rne(float f) {
    unsigned u = __builtin_bit_cast(unsigned, f);
    u += 0x7fffu + ((u >> 16) & 1u);
    return (unsigned short)(u >> 16);
}

__device__ __forceinline__ float gelu_f(float v) {
    // tanh-form GELU: v*sigmoid(2t), t = 0.7978845608*(v + 0.044715 v^3)
    float t = v * __builtin_fmaf(v * v, 0.0356774081f, 0.7978845608f);
    float e = __builtin_amdgcn_exp2f(t * 2.8853900818f);   // e^{2t}
    float s = __builtin_amdgcn_rcpf(1.0f + e);
    return __builtin_fmaf(-v, s, v);                        // v - v/(1+e^{2t})
}

__device__ __forceinline__ void async_ld16(const void* gsrc, void* ldst) {
    __builtin_amdgcn_global_load_lds(
        (const __attribute__((address_space(1))) unsigned int*)(unsigned long long)(const char*)gsrc,
        (__attribute__((address_space(3))) unsigned int*)ldst,
        16, 0, 0);
}

// ---------------- Pre-pass 1: W1 [J][d][e] fp32 -> W1t [J][e=n][d=k] bf16 -----
__global__ void w1_transpose_kernel(const float* __restrict__ W1, ushort_t* __restrict__ W1t) {
    __shared__ ushort_t tile[64][74];   // 74: odd-dword stride -> conflict-free-ish
    const int j = blockIdx.z;
    const int t = threadIdx.x;          // 256
    const int d0 = blockIdx.x * 64, e0 = blockIdx.y * 64;
    const float* src = W1 + (size_t)j * D_DIM * D_DIM;
    const int el = t & 63, dl = t >> 6; // dl: 0..3
#pragma unroll
    for (int i = 0; i < 16; i++) {
        int d = dl + i * 4;
        tile[el][d] = bf16rne(src[(size_t)(d0 + d) * D_DIM + e0 + el]);
    }
    __syncthreads();
    ushort_t* dst = W1t + (size_t)j * D_DIM * D_DIM;
#pragma unroll
    for (int i = 0; i < 16; i++) {
        int n = dl + i * 4;
        dst[(size_t)(e0 + n) * D_DIM + d0 + el] = tile[n][el];
    }
}

// ---------------- Pre-pass 2: W2a/W2b -> W2t [J][16][512] bf16 (zero-padded o), b2 -> b2p [J][16]
__global__ void w2_pack_kernel(const float* __restrict__ W2a, const float* __restrict__ b2a,
                               const float* __restrict__ W2b, const float* __restrict__ b2b,
                               ushort_t* __restrict__ W2t, float* __restrict__ b2p) {
    const int j = blockIdx.x;
    const int t = threadIdx.x;
    const int odim = (j < J6) ? 6 : 3;
    const float* w = (j < J6) ? (W2a + (size_t)j * D_DIM * 6) : (W2b + (size_t)(j - J6) * D_DIM * 3);
    for (int idx = t; idx < 16 * D_DIM; idx += 256) {
        int o = idx >> 9, k = idx & 511;
        float v = (o < odim) ? w[(size_t)k * odim + o] : 0.0f;
        W2t[(size_t)j * 16 * D_DIM + idx] = bf16rne(v);
    }
    if (t < 16) {
        const float* bb = (j < J6) ? (b2a + (size_t)j * 6) : (b2b + (size_t)(j - J6) * 3);
        b2p[j * 16 + t] = (t < odim) ? bb[t] : 0.0f;
    }
}

// ---------------- Fused main kernel ------------------------------------------
// grid: (25 m-tiles, 43 joints), block 256 = 4 waves. Tile 128(m) x 128(n), BK=64.
__global__ __launch_bounds__(256, 2)
void MotionDecoder_36309653520632_kernel(const float* __restrict__ x,
                                         const float* __restrict__ b1,
                                         const ushort_t* __restrict__ W1t,
                                         const ushort_t* __restrict__ W2t,
                                         const float* __restrict__ b2p,
                                         float* __restrict__ out) {
    __shared__ unsigned char smem[32768];
    char* as_base = (char*)smem;              // A: [128 m][8 chunks of 16B] swizzled, 16 KB
    char* bs_base = (char*)smem + 16384;      // B: [128 n][8 chunks] swizzled, 16 KB
    char* hs_base = (char*)smem;              // h: [128 m][16 chunks] swizzled, 32 KB (alias)

    const int j   = blockIdx.y;
    const int m0  = blockIdx.x * 128;
    const int tid = threadIdx.x;
    const int lane = tid & 63;
    const int wid  = tid >> 6;
    const int wrow = (wid >> 1) * 64;
    const int wcol = (wid & 1) * 64;

    // A staging mapping: thread -> (row, 32-float half)
    const int a_m  = tid >> 1;
    const int a_k0 = (tid & 1) * 32;
    int a_row = m0 + a_m; if (a_row > BT - 1) a_row = BT - 1;
    const float* xrow = x + ((size_t)a_row * J_TOT + j) * D_DIM;

    const ushort_t* w1j = W1t + (size_t)j * D_DIM * D_DIM;
    const ushort_t* w2j = W2t + (size_t)j * 16 * D_DIM;

    f32x4 acc2[4];
#pragma unroll
    for (int r = 0; r < 4; r++) acc2[r] = (f32x4){0.f, 0.f, 0.f, 0.f};

    for (int nt = 0; nt < 4; nt++) {
        const int n0 = nt * 128;
        f32x4 acc[4][4];
#pragma unroll
        for (int a = 0; a < 4; a++)
#pragma unroll
            for (int b = 0; b < 4; b++) acc[a][b] = (f32x4){0.f, 0.f, 0.f, 0.f};

        for (int ks = 0; ks < 8; ks++) {
            // ---- stage B (async direct-to-LDS, pre-converted bf16, xor-swizzled source chunk)
#pragma unroll
            for (int pass = 0; pass < 4; pass++) {
                int n = pass * 32 + wid * 8 + (lane >> 3);
                int cg = (lane & 7) ^ (n & 7);
                const ushort_t* gsrc = w1j + (size_t)(n0 + n) * D_DIM + ks * 64 + cg * 8;
                char* ldst = bs_base + (pass * 32 + wid * 8) * 128;  // wave-uniform base
                async_ld16(gsrc, ldst);
            }
            // ---- stage A (fp32 load -> bf16 convert -> LDS, xor-swizzled)
            const float* ap = xrow + ks * 64 + a_k0;
            float4 f[8];
#pragma unroll
            for (int i = 0; i < 8; i++) f[i] = ((const float4*)ap)[i];
#pragma unroll
            for (int c = 0; c < 4; c++) {
                union { unsigned short s[8]; uint4 v; } pk;
                float4 u0 = f[2 * c], u1 = f[2 * c + 1];
                pk.s[0] = bf16rne(u0.x); pk.s[1] = bf16rne(u0.y);
                pk.s[2] = bf16rne(u0.z); pk.s[3] = bf16rne(u0.w);
                pk.s[4] = bf16rne(u1.x); pk.s[5] = bf16rne(u1.y);
                pk.s[6] = bf16rne(u1.z); pk.s[7] = bf16rne(u1.w);
                int ch = (a_k0 >> 3) + c;            // 0..7
                int sw = ch ^ (a_m & 7);
                *(uint4*)(as_base + a_m * 128 + sw * 16) = pk.v;
            }
            __syncthreads();
            // ---- compute: 2 x (4 a-frags, 4 b-frags, 16 MFMA)
#pragma unroll
            for (int kk = 0; kk < 2; kk++) {
                short8 af[4], bfr[4];
                int chv = kk * 4 + (lane >> 4);
#pragma unroll
                for (int rt = 0; rt < 4; rt++) {
                    int m = wrow + rt * 16 + (lane & 15);
                    af[rt] = *(const short8*)(as_base + m * 128 + ((chv ^ (m & 7)) * 16));
                }
#pragma unroll
                for (int ct = 0; ct < 4; ct++) {
                    int n = wcol + ct * 16 + (lane & 15);
                    bfr[ct] = *(const short8*)(bs_base + n * 128 + ((chv ^ (n & 7)) * 16));
                }
#pragma unroll
                for (int rt = 0; rt < 4; rt++)
#pragma unroll
                    for (int ct = 0; ct < 4; ct++)
                        acc[rt][ct] = __builtin_amdgcn_mfma_f32_16x16x32_bf16(
                            af[rt], bfr[ct], acc[rt][ct], 0, 0, 0);
            }
            __syncthreads();
        }

        // ---- bias + GELU + write h (bf16) into LDS (aliases A/B staging)
#pragma unroll
        for (int ct = 0; ct < 4; ct++) {
            int ncol = wcol + ct * 16 + (lane & 15);
            float bv = b1[j * D_DIM + n0 + ncol];
            int c2 = ncol >> 3;
            int boff = (ncol & 7) * 2;
#pragma unroll
            for (int rt = 0; rt < 4; rt++) {
                int mb = wrow + rt * 16 + ((lane >> 4) << 2);
#pragma unroll
                for (int r = 0; r < 4; r++) {
                    float g = gelu_f(acc[rt][ct][r] + bv);
                    int m = mb + r;
                    int sw = c2 ^ (m & 15);
                    *(unsigned short*)(hs_base + m * 256 + sw * 16 + boff) = bf16rne(g);
                }
            }
        }
        __syncthreads();

        // ---- layer 2: waves 0,1 do rows 0-63 / 64-127, K = this 128-col slab
        if (wid < 2) {
            short8 wf[4];
#pragma unroll
            for (int kk2 = 0; kk2 < 4; kk2++) {
                const ushort_t* gsrc = w2j + (size_t)(lane & 15) * D_DIM + n0 + kk2 * 32 + (lane >> 4) * 8;
                wf[kk2] = *(const short8*)gsrc;
            }
#pragma unroll
            for (int rt = 0; rt < 4; rt++) {
                int m = wid * 64 + rt * 16 + (lane & 15);
#pragma unroll
                for (int kk2 = 0; kk2 < 4; kk2++) {
                    int ch = kk2 * 4 + (lane >> 4);
                    short8 a2 = *(const short8*)(hs_base + m * 256 + ((ch ^ (m & 15)) * 16));
                    acc2[rt] = __builtin_amdgcn_mfma_f32_16x16x32_bf16(a2, wf[kk2], acc2[rt], 0, 0, 0);
                }
            }
        }
        __syncthreads();
    }

    // ---- epilogue: out[m, colbase + o] = acc2 + b2
    if (wid < 2) {
        int o = lane & 15;
        int odim = (j < J6) ? 6 : 3;
        int cb = (j < J6) ? j * 6 : 78 + (j - J6) * 3;
        float bo = b2p[j * 16 + o];
        if (o < odim) {
#pragma unroll
            for (int rt = 0; rt < 4; rt++) {
#pragma unroll
                for (int r = 0; r < 4; r++) {
                    int m = m0 + wid * 64 + rt * 16 + ((lane >> 4) << 2) + r;
                    if (m < BT) out[(size_t)m * OUTW + cb + o] = acc2[rt][r] + bo;
                }
            }
        }
    }
}

extern "C" void kernel_launch(void* const* d_in, const int* in_sizes, int n_in,
                              void* d_out, int out_size, void* d_ws, size_t ws_size,
                              hipStream_t stream) {
    const float* x   = (const float*)d_in[0];
    const float* W1  = (const float*)d_in[1];
    const float* b1  = (const float*)d_in[2];
    const float* W2a = (const float*)d_in[3];
    const float* b2a = (const float*)d_in[4];
    const float* W2b = (const float*)d_in[5];
    const float* b2b = (const float*)d_in[6];
    float* out = (float*)d_out;

    // workspace layout
    ushort_t* W1t = (ushort_t*)d_ws;                       // 43*512*512*2 = 22,544,384 B
    ushort_t* W2t = W1t + (size_t)J_TOT * D_DIM * D_DIM;   // 43*16*512*2  =    704,512 B
    float*    b2p = (float*)(W2t + (size_t)J_TOT * 16 * D_DIM); // 43*16*4 = 2752 B

    w1_transpose_kernel<<<dim3(8, 8, J_TOT), 256, 0, stream>>>(W1, W1t);
    w2_pack_kernel<<<J_TOT, 256, 0, stream>>>(W2a, b2a, W2b, b2b, W2t, b2p);
    MotionDecoder_36309653520632_kernel<<<dim3(25, J_TOT), 256, 0, stream>>>(
        x, b1, W1t, W2t, b2p, out);
}